// Round 18
// baseline (259.576 us; speedup 1.0000x reference)
//
#include <hip/hip_runtime.h>
#include <hip/hip_bf16.h>
#include <stdint.h>

#define EPS 1e-5f
#define NOUT 2338   // 2048+256+32+1+1 output cols per batch row

typedef __bf16 bf16x8 __attribute__((ext_vector_type(8)));
typedef float f32x4 __attribute__((ext_vector_type(4)));
typedef unsigned short u16;

__device__ __forceinline__ uint32_t pack2f(float lo, float hi) {
  union { __bf16 h[2]; uint32_t u; } r;
  r.h[0] = (__bf16)lo;   // v_cvt_pk_bf16_f32
  r.h[1] = (__bf16)hi;
  return r.u;
}

// ---------------- kernel 0: x [256][3008] f32 -> bf16, packed in MFMA B-frag tile order
// XBp[ks][kb][m][e] : ks in [0,94), kb in [0,4), m in [0,256), e in [0,8)
__global__ __launch_bounds__(256) void cvt_pack_kernel(const float* __restrict__ x,
                                                       u16* __restrict__ xbp) {
  const int i = blockIdx.x * 256 + threadIdx.x;   // 96256 total
  const int ks = i >> 10;
  const int rem = i & 1023;
  const int kb = rem >> 8;
  const int m = rem & 255;
  const f32x4* src = (const f32x4*)(x + (size_t)m * 3008 + ks * 32 + kb * 8);
  f32x4 a = src[0], b = src[1];
  uint4 o;
  o.x = pack2f(a.x, a.y);
  o.y = pack2f(a.z, a.w);
  o.z = pack2f(b.x, b.y);
  o.w = pack2f(b.z, b.w);
  ((uint4*)xbp)[i] = o;
}

// ---------------- kernel 1: leaf GEMM — 128-row reuse + bf16 W slab = 48KB, 3 blocks/CU.
// C [20480 x 256] = W[20480 x 3008] * X^T.  16x16x32 bf16 MFMA.
// Grid 640: bid>>2 = 128-row tile (n0), bid&3 = K-quarter (24/24/23/23 steps).
// Block 256 thr (4 waves). Wave w: rh=w>>1 (64 rows = 4 A-frags), mh=w&1 (8 m-tiles).
// Per wave-step: 8 B-frag reads feed 4 A-frags -> 32 MFMA (0.375 b128/MFMA).
// X: 2x16KB dbuf via global_load_lds. W: reg-staged f32 -> bf16 into 2x8KB LDS
// [row(128)][slot(4)][8 bf16], slot = ks ^ (row&3) (bank spread). A-frag = 1 ds_read_b128.
__global__ __launch_bounds__(256, 3) void gemm_leaf(const float* __restrict__ W,
                                                    const float* __restrict__ gb,
                                                    const u16* __restrict__ XBp,
                                                    float* __restrict__ hout) {
  __shared__ __align__(16) u16 xl[2][8192];   // 2 x 16KB X tile [kb][m][e]
  __shared__ __align__(16) u16 wl[2][4096];   // 2 x 8KB  W slab [row(128)][slot(4)][8] bf16
  const int tid = threadIdx.x;
  const int w = tid >> 6;
  const int lane = tid & 63;
  const int rh = w >> 1;          // row-half 0..1 (64 rows)
  const int mh = w & 1;           // m-half 0..1
  const int lquad = lane >> 4;    // k-group 0..3
  const int lmod = lane & 15;
  const int n0 = (blockIdx.x >> 2) * 128;
  const int kh = blockIdx.x & 3;
  const int kbase = kh * 24 - ((kh > 2) ? (kh - 2) : 0);   // 0,24,48,71
  const int nst = 24 - ((kh >= 2) ? 1 : 0);                // 24,24,23,23

  f32x4 acc[4][8];
#pragma unroll
  for (int a = 0; a < 4; ++a)
#pragma unroll
    for (int j = 0; j < 8; ++j) acc[a][j] = (f32x4){0.f, 0.f, 0.f, 0.f};

  // X stage: 16 coalesced 1KB gll (4 per wave)
#define STAGE_X(ks, buf)                                                                \
  do {                                                                                  \
    _Pragma("unroll")                                                                   \
    for (int p = 0; p < 4; ++p) {                                                       \
      const int c = (w * 4 + p) * 64;                                                   \
      const u16* src = XBp + (size_t)(ks) * 8192 + (size_t)(c + lane) * 8;              \
      u16* dst = &xl[buf][(size_t)c * 8];                                               \
      __builtin_amdgcn_global_load_lds((const __attribute__((address_space(1))) void*)src, \
                                       (__attribute__((address_space(3))) void*)dst,    \
                                       16, 0, 0);                                       \
    }                                                                                   \
  } while (0)

  // W reg-stage: wave w covers rows w*32 .. w*32+31. Lane: wks=lane>>4 (k-slice),
  // wrl=lane&15; rows w*32+wrl and w*32+wrl+16, 8 floats each (2 f32x4).
  const int wks = lane >> 4;
  const int wrl = lane & 15;
  const int wrow0 = w * 32 + wrl;
  const int wrow1 = wrow0 + 16;
  const float* wg0 = W + (size_t)(n0 + wrow0) * 3008 + wks * 8;
  const float* wg1 = W + (size_t)(n0 + wrow1) * 3008 + wks * 8;
  const int wo0 = wrow0 * 32 + ((wks ^ (wrow0 & 3)) * 8);   // u16 offset
  const int wo1 = wrow1 * 32 + ((wks ^ (wrow1 & 3)) * 8);

#define LOADW(ks, dA0, dA1, dB0, dB1)                                                   \
  do {                                                                                  \
    const f32x4* a0 = (const f32x4*)(wg0 + (size_t)(ks) * 32);                          \
    dA0 = a0[0]; dA1 = a0[1];                                                           \
    const f32x4* a1 = (const f32x4*)(wg1 + (size_t)(ks) * 32);                          \
    dB0 = a1[0]; dB1 = a1[1];                                                           \
  } while (0)

#define WRITEW(buf, dA0, dA1, dB0, dB1)                                                 \
  do {                                                                                  \
    union { uint32_t u[4]; bf16x8 v; } c0, c1;                                          \
    c0.u[0] = pack2f(dA0.x, dA0.y); c0.u[1] = pack2f(dA0.z, dA0.w);                     \
    c0.u[2] = pack2f(dA1.x, dA1.y); c0.u[3] = pack2f(dA1.z, dA1.w);                     \
    c1.u[0] = pack2f(dB0.x, dB0.y); c1.u[1] = pack2f(dB0.z, dB0.w);                     \
    c1.u[2] = pack2f(dB1.x, dB1.y); c1.u[3] = pack2f(dB1.z, dB1.w);                     \
    *(bf16x8*)(&wl[buf][wo0]) = c0.v;                                                   \
    *(bf16x8*)(&wl[buf][wo1]) = c1.v;                                                   \
  } while (0)

#define COMPUTE(buf)                                                                    \
  do {                                                                                  \
    const u16* xb = &xl[buf][(size_t)lquad * 2048 + mh * 1024 + lmod * 8];              \
    bf16x8 af[4];                                                                       \
    _Pragma("unroll")                                                                   \
    for (int a = 0; a < 4; ++a) {                                                       \
      const int row = rh * 64 + a * 16 + lmod;                                          \
      af[a] = *(const bf16x8*)(&wl[buf][row * 32 + ((lquad ^ (row & 3)) * 8)]);         \
    }                                                                                   \
    _Pragma("unroll")                                                                   \
    for (int j = 0; j < 8; ++j) {                                                       \
      const bf16x8 bfrag = *(const bf16x8*)(xb + j * 128);                              \
      acc[0][j] = __builtin_amdgcn_mfma_f32_16x16x32_bf16(af[0], bfrag, acc[0][j], 0, 0, 0); \
      acc[1][j] = __builtin_amdgcn_mfma_f32_16x16x32_bf16(af[1], bfrag, acc[1][j], 0, 0, 0); \
      acc[2][j] = __builtin_amdgcn_mfma_f32_16x16x32_bf16(af[2], bfrag, acc[2][j], 0, 0, 0); \
      acc[3][j] = __builtin_amdgcn_mfma_f32_16x16x32_bf16(af[3], bfrag, acc[3][j], 0, 0, 0); \
    }                                                                                   \
  } while (0)

  // prologue: W(kbase) reg-loads (4), X(kbase) gll (4); W regs ready at vmcnt(4).
  {
    f32x4 wA0, wA1, wB0, wB1;
    LOADW(kbase, wA0, wA1, wB0, wB1);
    __builtin_amdgcn_sched_barrier(0);
    STAGE_X(kbase, 0);
    __builtin_amdgcn_sched_barrier(0);
    asm volatile("s_waitcnt vmcnt(4)" ::: "memory");
    __builtin_amdgcn_sched_barrier(0);
    WRITEW(0, wA0, wA1, wB0, wB1);
  }

  for (int s = 0; s < nst; ++s) {
    __syncthreads();   // X(s) staged + W(s) ds_writes visible
    f32x4 nA0 = {0,0,0,0}, nA1 = {0,0,0,0}, nB0 = {0,0,0,0}, nB1 = {0,0,0,0};
    if (s + 1 < nst) LOADW(kbase + s + 1, nA0, nA1, nB0, nB1);   // oldest 4
    __builtin_amdgcn_sched_barrier(0);
    if (s + 1 < nst) STAGE_X(kbase + s + 1, (s + 1) & 1);        // newer 4 gll
    __builtin_amdgcn_sched_barrier(0);
    COMPUTE(s & 1);
    if (s + 1 < nst) {
      asm volatile("s_waitcnt vmcnt(4)" ::: "memory");  // W regs done, X gll fly
      __builtin_amdgcn_sched_barrier(0);
      WRITEW((s + 1) & 1, nA0, nA1, nB0, nB1);
    }
  }

#undef COMPUTE
#undef WRITEW
#undef LOADW
#undef STAGE_X

  // store partial: hp = hout + kh*20480*256; kh==0 adds gb.
  float* hp = hout + (size_t)kh * 20480 * 256;
#pragma unroll
  for (int a = 0; a < 4; ++a) {
    const int r0 = n0 + rh * 64 + a * 16 + lquad * 4;
    float gb4[4];
#pragma unroll
    for (int r2 = 0; r2 < 4; ++r2) gb4[r2] = (kh == 0) ? gb[r0 + r2] : 0.f;
#pragma unroll
    for (int j = 0; j < 8; ++j) {
      const int col = (mh * 8 + j) * 16 + lmod;
#pragma unroll
      for (int r2 = 0; r2 < 4; ++r2) {
        hp[(size_t)(r0 + r2) * 256 + col] = acc[a][j][r2] + gb4[r2];
      }
    }
  }
}

// ---------------- level 0: one term per block, sums the four K-quarter partials
__global__ __launch_bounds__(256) void level0_kernel(
    const float* __restrict__ yin, const float* __restrict__ w,
    const float* __restrict__ bia, const float* __restrict__ gam,
    const float* __restrict__ bet, const float* __restrict__ p,
    const float* __restrict__ q, const float* __restrict__ r,
    const float* __restrict__ s, float* __restrict__ yout,
    float* __restrict__ out, int inl, int off) {
  const int t = blockIdx.x;
  const int b = threadIdx.x;
  const size_t P = (size_t)20480 * 256;
  __shared__ float wls[6 * 10];
  __shared__ float part[4][12];
  __shared__ float stats[12];
  const float* wt = w + (size_t)t * 6 * inl;
  for (int i = b; i < 6 * inl; i += 256) wls[i] = wt[i];
  __syncthreads();

  float z[6];
#pragma unroll
  for (int h = 0; h < 6; ++h) z[h] = bia[t * 6 + h];
  const float* yp = yin + (size_t)t * inl * 256 + b;
  for (int i = 0; i < inl; ++i) {
    const size_t o = (size_t)i * 256;
    float v = yp[o] + yp[P + o] + yp[2 * P + o] + yp[3 * P + o];
#pragma unroll
    for (int h = 0; h < 6; ++h) z[h] = fmaf(v, wls[h * inl + i], z[h]);
  }
#pragma unroll
  for (int h = 0; h < 6; ++h) z[h] = tanhf(z[h]);

  float sm[6], sq[6];
#pragma unroll
  for (int h = 0; h < 6; ++h) { sm[h] = z[h]; sq[h] = z[h] * z[h]; }
#pragma unroll
  for (int o = 32; o > 0; o >>= 1) {
#pragma unroll
    for (int h = 0; h < 6; ++h) {
      sm[h] += __shfl_down(sm[h], o);
      sq[h] += __shfl_down(sq[h], o);
    }
  }
  const int lane = b & 63, wvi = b >> 6;
  if (lane == 0) {
#pragma unroll
    for (int h = 0; h < 6; ++h) { part[wvi][h] = sm[h]; part[wvi][6 + h] = sq[h]; }
  }
  __syncthreads();
  if (b < 6) {
    float msum = part[0][b] + part[1][b] + part[2][b] + part[3][b];
    float qsum = part[0][6 + b] + part[1][6 + b] + part[2][6 + b] + part[3][6 + b];
    float m = msum * (1.f / 256.f);
    float var = qsum * (1.f / 256.f) - m * m;
    stats[b] = m;
    stats[6 + b] = rsqrtf(var + EPS);
  }
  __syncthreads();

  float a = q[t];
#pragma unroll
  for (int h = 0; h < 6; ++h) {
    float yy = (z[h] - stats[h]) * stats[6 + h] * gam[t * 6 + h] + bet[t * 6 + h];
    yout[((size_t)t * 6 + h) * 256 + b] = yy;
    a = fmaf(yy, p[t * 6 + h], a);
  }
  out[(size_t)b * NOUT + off + t] = tanhf(a) * r[t] + s[t];
}

// ---------------- levels 1..2: one term per block
__global__ __launch_bounds__(256) void level_kernel(
    const float* __restrict__ yin, const float* __restrict__ w,
    const float* __restrict__ bia, const float* __restrict__ gam,
    const float* __restrict__ bet, const float* __restrict__ p,
    const float* __restrict__ q, const float* __restrict__ r,
    const float* __restrict__ s, float* __restrict__ yout,
    float* __restrict__ out, int inl, int off) {
  const int t = blockIdx.x;
  const int b = threadIdx.x;
  __shared__ float wls[6 * 48];
  __shared__ float part[4][12];
  __shared__ float stats[12];
  const float* wt = w + (size_t)t * 6 * inl;
  for (int i = b; i < 6 * inl; i += 256) wls[i] = wt[i];
  __syncthreads();

  float z[6];
#pragma unroll
  for (int h = 0; h < 6; ++h) z[h] = bia[t * 6 + h];
  const float* yp = yin + (size_t)t * inl * 256 + b;
  for (int i = 0; i < inl; ++i) {
    float v = yp[(size_t)i * 256];
#pragma unroll
    for (int h = 0; h < 6; ++h) z[h] = fmaf(v, wls[h * inl + i], z[h]);
  }
#pragma unroll
  for (int h = 0; h < 6; ++h) z[h] = tanhf(z[h]);

  float sm[6], sq[6];
#pragma unroll
  for (int h = 0; h < 6; ++h) { sm[h] = z[h]; sq[h] = z[h] * z[h]; }
#pragma unroll
  for (int o = 32; o > 0; o >>= 1) {
#pragma unroll
    for (int h = 0; h < 6; ++h) {
      sm[h] += __shfl_down(sm[h], o);
      sq[h] += __shfl_down(sq[h], o);
    }
  }
  const int lane = b & 63, wvi = b >> 6;
  if (lane == 0) {
#pragma unroll
    for (int h = 0; h < 6; ++h) { part[wvi][h] = sm[h]; part[wvi][6 + h] = sq[h]; }
  }
  __syncthreads();
  if (b < 6) {
    float msum = part[0][b] + part[1][b] + part[2][b] + part[3][b];
    float qsum = part[0][6 + b] + part[1][6 + b] + part[2][6 + b] + part[3][6 + b];
    float m = msum * (1.f / 256.f);
    float var = qsum * (1.f / 256.f) - m * m;
    stats[b] = m;
    stats[6 + b] = rsqrtf(var + EPS);
  }
  __syncthreads();

  float a = q[t];
#pragma unroll
  for (int h = 0; h < 6; ++h) {
    float yy = (z[h] - stats[h]) * stats[6 + h] * gam[t * 6 + h] + bet[t * 6 + h];
    yout[((size_t)t * 6 + h) * 256 + b] = yy;
    a = fmaf(yy, p[t * 6 + h], a);
  }
  out[(size_t)b * NOUT + off + t] = tanhf(a) * r[t] + s[t];
}

// ---------------- merged level-3 (inl=192, 1 term) + final head; single block
__global__ __launch_bounds__(256) void level3_final_kernel(
    const float* __restrict__ y2,
    const float* __restrict__ w3, const float* __restrict__ b3,
    const float* __restrict__ g3, const float* __restrict__ e3,
    const float* __restrict__ p3, const float* __restrict__ q3,
    const float* __restrict__ r3, const float* __restrict__ s3,
    const float* __restrict__ fw, const float* __restrict__ fb,
    const float* __restrict__ fg, const float* __restrict__ fe,
    const float* __restrict__ pw, const float* __restrict__ pb,
    const float* __restrict__ rw, const float* __restrict__ rb,
    float* __restrict__ out) {
  const int b = threadIdx.x;
  __shared__ float wls[6 * 192];
  __shared__ float part[4][24];
  __shared__ float stats[24];
  for (int i = b; i < 6 * 192; i += 256) wls[i] = w3[i];
  __syncthreads();

  float z[6];
#pragma unroll
  for (int h = 0; h < 6; ++h) z[h] = b3[h];
  const float* yp = y2 + b;
  for (int i = 0; i < 192; ++i) {
    float v = yp[(size_t)i * 256];
#pragma unroll
    for (int h = 0; h < 6; ++h) z[h] = fmaf(v, wls[h * 192 + i], z[h]);
  }
#pragma unroll
  for (int h = 0; h < 6; ++h) z[h] = tanhf(z[h]);

  const int lane = b & 63, wvi = b >> 6;
  {
    float sm[6], sq[6];
#pragma unroll
    for (int h = 0; h < 6; ++h) { sm[h] = z[h]; sq[h] = z[h] * z[h]; }
#pragma unroll
    for (int o = 32; o > 0; o >>= 1) {
#pragma unroll
      for (int h = 0; h < 6; ++h) {
        sm[h] += __shfl_down(sm[h], o);
        sq[h] += __shfl_down(sq[h], o);
      }
    }
    if (lane == 0) {
#pragma unroll
      for (int h = 0; h < 6; ++h) { part[wvi][h] = sm[h]; part[wvi][6 + h] = sq[h]; }
    }
    __syncthreads();
    if (b < 6) {
      float msum = part[0][b] + part[1][b] + part[2][b] + part[3][b];
      float qsum = part[0][6 + b] + part[1][6 + b] + part[2][6 + b] + part[3][6 + b];
      float m = msum * (1.f / 256.f);
      float var = qsum * (1.f / 256.f) - m * m;
      stats[b] = m;
      stats[6 + b] = rsqrtf(var + EPS);
    }
    __syncthreads();
  }

  float yr[6];
  float a3 = q3[0];
#pragma unroll
  for (int h = 0; h < 6; ++h) {
    yr[h] = (z[h] - stats[h]) * stats[6 + h] * g3[h] + e3[h];
    a3 = fmaf(yr[h], p3[h], a3);
  }
  out[(size_t)b * NOUT + 2336] = tanhf(a3) * r3[0] + s3[0];
  __syncthreads();

  float zf[12];
#pragma unroll
  for (int j = 0; j < 12; ++j) {
    float a = fb[j];
#pragma unroll
    for (int h = 0; h < 6; ++h) a = fmaf(yr[h], fw[j * 6 + h], a);
    zf[j] = tanhf(a);
  }
  {
    float sm[12], sq[12];
#pragma unroll
    for (int j = 0; j < 12; ++j) { sm[j] = zf[j]; sq[j] = zf[j] * zf[j]; }
#pragma unroll
    for (int o = 32; o > 0; o >>= 1) {
#pragma unroll
      for (int j = 0; j < 12; ++j) {
        sm[j] += __shfl_down(sm[j], o);
        sq[j] += __shfl_down(sq[j], o);
      }
    }
    if (lane == 0) {
#pragma unroll
      for (int j = 0; j < 12; ++j) { part[wvi][j] = sm[j]; part[wvi][12 + j] = sq[j]; }
    }
    __syncthreads();
    if (b < 12) {
      float msum = part[0][b] + part[1][b] + part[2][b] + part[3][b];
      float qsum = part[0][12 + b] + part[1][12 + b] + part[2][12 + b] + part[3][12 + b];
      float m = msum * (1.f / 256.f);
      float var = qsum * (1.f / 256.f) - m * m;
      stats[b] = m;
      stats[12 + b] = rsqrtf(var + EPS);
    }
    __syncthreads();
  }
  float a = pb[0];
#pragma unroll
  for (int j = 0; j < 12; ++j) {
    float of = (zf[j] - stats[j]) * stats[12 + j] * fg[j] + fe[j];
    a = fmaf(of, pw[j], a);
  }
  out[(size_t)b * NOUT + 2337] = tanhf(a) * rw[0] + rb[0];
}

extern "C" void kernel_launch(void* const* d_in, const int* in_sizes, int n_in,
                              void* d_out, int out_size, void* d_ws, size_t ws_size,
                              hipStream_t stream) {
  const float* x  = (const float*)d_in[0];
  const float* gW = (const float*)d_in[1];
  const float* gb = (const float*)d_in[2];
  float* out = (float*)d_out;

  char* wsb = (char*)d_ws;
  u16* XBp = (u16*)wsb;                              // 256*3008 bf16 (packed) = 1.54MB
  float* h0 = (float*)(wsb + 1540096);               // 4 x [20480][256] K-quarter partials
  float* y0 = h0 + (size_t)4 * 20480 * 256;          // [12288][256]
  float* y1 = y0 + (size_t)12288 * 256;              // [1536][256]
  float* y2 = y1 + (size_t)1536 * 256;               // [192][256]

  cvt_pack_kernel<<<dim3(376), dim3(256), 0, stream>>>(x, XBp);
  gemm_leaf<<<dim3(640), dim3(256), 0, stream>>>(gW, gb, XBp, h0);

  level0_kernel<<<dim3(2048), dim3(256), 0, stream>>>(
      h0,
      (const float*)d_in[3], (const float*)d_in[4], (const float*)d_in[5],
      (const float*)d_in[6], (const float*)d_in[7], (const float*)d_in[8],
      (const float*)d_in[9], (const float*)d_in[10], y0, out, 10, 0);

#define LV(base, yin, yout, inl, off, grid)                                           \
  level_kernel<<<dim3(grid), dim3(256), 0, stream>>>(                                 \
      yin, (const float*)d_in[base], (const float*)d_in[base + 1],                    \
      (const float*)d_in[base + 2], (const float*)d_in[base + 3],                     \
      (const float*)d_in[base + 4], (const float*)d_in[base + 5],                     \
      (const float*)d_in[base + 6], (const float*)d_in[base + 7], yout, out, inl, off)

  LV(11, y0, y1, 48,  2048, 256);
  LV(19, y1, y2, 48,  2304, 32);
#undef LV

  level3_final_kernel<<<dim3(1), dim3(256), 0, stream>>>(
      y2,
      (const float*)d_in[27], (const float*)d_in[28], (const float*)d_in[29],
      (const float*)d_in[30], (const float*)d_in[31], (const float*)d_in[32],
      (const float*)d_in[33], (const float*)d_in[34],
      (const float*)d_in[35], (const float*)d_in[36], (const float*)d_in[37],
      (const float*)d_in[38], (const float*)d_in[39], (const float*)d_in[40],
      (const float*)d_in[41], (const float*)d_in[42], out);
}

// Round 19
// 137.548 us; speedup vs baseline: 1.8872x; 1.8872x over previous
//
#include <hip/hip_runtime.h>
#include <hip/hip_bf16.h>
#include <stdint.h>

#define EPS 1e-5f
#define NOUT 2338   // 2048+256+32+1+1 output cols per batch row

typedef __bf16 bf16x8 __attribute__((ext_vector_type(8)));
typedef float f32x4 __attribute__((ext_vector_type(4)));
typedef unsigned short u16;

__device__ __forceinline__ uint32_t pack2f(float lo, float hi) {
  union { __bf16 h[2]; uint32_t u; } r;
  r.h[0] = (__bf16)lo;   // compiler emits v_cvt_pk_bf16_f32 (RNE) for cast pairs
  r.h[1] = (__bf16)hi;
  return r.u;
}

// ---------------- kernel 0: x [256][3008] f32 -> bf16, packed in MFMA B-frag tile order
// XBp[ks][kb][m][e] : ks in [0,94), kb in [0,4), m in [0,256), e in [0,8)
__global__ __launch_bounds__(256) void cvt_pack_kernel(const float* __restrict__ x,
                                                       u16* __restrict__ xbp) {
  const int i = blockIdx.x * 256 + threadIdx.x;   // 96256 total
  const int ks = i >> 10;
  const int rem = i & 1023;
  const int kb = rem >> 8;
  const int m = rem & 255;
  const f32x4* src = (const f32x4*)(x + (size_t)m * 3008 + ks * 32 + kb * 8);
  f32x4 a = src[0], b = src[1];
  uint4 o;
  o.x = pack2f(a.x, a.y);
  o.y = pack2f(a.z, a.w);
  o.z = pack2f(b.x, b.y);
  o.w = pack2f(b.z, b.w);
  ((uint4*)xbp)[i] = o;
}

// ---------------- kernel 1: leaf GEMM — LDS-traffic-optimized, K-split 2. (R12 structure)
// C [20480 x 256] = W[20480 x 3008] * X^T.  16x16x32 bf16 MFMA.
// Grid 640: bid>>1 = 64-row tile (n0), bid&1 = K-half (47 of 94 k-steps).
// Block 256 thr (4 waves). Wave w: rh=w>>1 (32 rows = 2 A-frags), mh=w&1 (8 m-tiles).
// Per wave per 32k-step: 8 B-frag + 4 W-frag ds_read_b128, 16 MFMA.
// A-frag f32->bf16 via native casts (v_cvt_pk_bf16_f32), not integer ops.
__global__ __launch_bounds__(256, 3) void gemm_leaf(const float* __restrict__ W,
                                                    const float* __restrict__ gb,
                                                    const u16* __restrict__ XBp,
                                                    float* __restrict__ hout) {
  __shared__ __align__(16) u16 xl[2][8192];     // 2 x 16KB X tile [kb][m][e]
  __shared__ __align__(16) float wlds[2][2048]; // 2 x 8KB W slab [row(64)][32f] swizzled
  const int tid = threadIdx.x;
  const int w = tid >> 6;
  const int lane = tid & 63;
  const int rh = w >> 1;          // row-half 0..1 (32 rows)
  const int mh = w & 1;           // m-half 0..1
  const int lquad = lane >> 4;    // k-group 0..3
  const int lmod = lane & 15;
  const int n0 = (blockIdx.x >> 1) * 64;
  const int kh = blockIdx.x & 1;
  const int kbase = kh * 47;

  f32x4 acc[2][8];
#pragma unroll
  for (int a = 0; a < 2; ++a)
#pragma unroll
    for (int j = 0; j < 8; ++j) acc[a][j] = (f32x4){0.f, 0.f, 0.f, 0.f};

  // X stage: 16 coalesced 1KB chunks (4 per wave); chunk c = (w*4+p)*64 lanes of 8 u16
#define STAGE_X(ks, buf)                                                                \
  {                                                                                     \
    _Pragma("unroll")                                                                   \
    for (int p = 0; p < 4; ++p) {                                                       \
      const int c = (w * 4 + p) * 64;                                                   \
      const u16* src = XBp + (size_t)(ks) * 8192 + (size_t)(c + lane) * 8;              \
      u16* dst = &xl[buf][(size_t)c * 8];                                               \
      __builtin_amdgcn_global_load_lds((const __attribute__((address_space(1))) void*)src, \
                                       (__attribute__((address_space(3))) void*)dst,    \
                                       16, 0, 0);                                       \
    }                                                                                   \
  }

  // W stage: 8 coalesced 1KB instrs (2 per wave); instr q covers rows q*8..q*8+7.
  // LDS[row][b] = W[n0+row][ks*32f + ((b ^ ((row&7)<<4))>>2)] via pre-swizzled source.
  const int wr0 = w * 2, wr1 = w * 2 + 1;
  const int lrow = lane >> 3;                                   // row-in-instr 0..7
  const int lswf = ((((lane & 7) * 16) ^ (lrow << 4)) >> 2);    // src float offset
  const float* wsrc0 = W + (size_t)(n0 + wr0 * 8 + lrow) * 3008 + lswf;
  const float* wsrc1 = W + (size_t)(n0 + wr1 * 8 + lrow) * 3008 + lswf;
#define STAGE_W(ks, buf)                                                                \
  {                                                                                     \
    __builtin_amdgcn_global_load_lds(                                                   \
        (const __attribute__((address_space(1))) void*)(wsrc0 + (size_t)(ks) * 32),     \
        (__attribute__((address_space(3))) void*)&wlds[buf][wr0 * 256], 16, 0, 0);      \
    __builtin_amdgcn_global_load_lds(                                                   \
        (const __attribute__((address_space(1))) void*)(wsrc1 + (size_t)(ks) * 32),     \
        (__attribute__((address_space(3))) void*)&wlds[buf][wr1 * 256], 16, 0, 0);      \
  }

  STAGE_X(kbase, 0);
  STAGE_W(kbase, 0);

  const int xorv = (lmod & 7) << 4;
  for (int s = 0; s < 47; ++s) {
    const int buf = s & 1;
    __syncthreads();   // drains stage(s)
    if (s < 46) {
      STAGE_X(kbase + s + 1, buf ^ 1);
      STAGE_W(kbase + s + 1, buf ^ 1);
    }
    __builtin_amdgcn_sched_barrier(0);   // stage issues before compute

    const float* wbase = &wlds[buf][0];
    const u16* xb = &xl[buf][(size_t)lquad * 2048 + mh * 1024 + lmod * 8];
    union { uint32_t u32[4]; bf16x8 v; } af[2];
#pragma unroll
    for (int a = 0; a < 2; ++a) {
      const int row = rh * 32 + a * 16 + lmod;
      const int fb = row * 32;
      const f32x4 wlo = *(const f32x4*)(wbase + fb + (((lquad * 32) ^ xorv) >> 2));
      const f32x4 whi = *(const f32x4*)(wbase + fb + (((lquad * 32 + 16) ^ xorv) >> 2));
      af[a].u32[0] = pack2f(wlo.x, wlo.y);
      af[a].u32[1] = pack2f(wlo.z, wlo.w);
      af[a].u32[2] = pack2f(whi.x, whi.y);
      af[a].u32[3] = pack2f(whi.z, whi.w);
    }
#pragma unroll
    for (int j = 0; j < 8; ++j) {
      const bf16x8 bfrag = *(const bf16x8*)(xb + j * 128);
      acc[0][j] = __builtin_amdgcn_mfma_f32_16x16x32_bf16(af[0].v, bfrag, acc[0][j], 0, 0, 0);
      acc[1][j] = __builtin_amdgcn_mfma_f32_16x16x32_bf16(af[1].v, bfrag, acc[1][j], 0, 0, 0);
    }
  }

#undef STAGE_W
#undef STAGE_X

  // store partial: hp = hout + kh*20480*256; kh==0 adds gb.
  float* hp = hout + (size_t)kh * 20480 * 256;
#pragma unroll
  for (int a = 0; a < 2; ++a) {
    const int r0 = n0 + rh * 32 + a * 16 + lquad * 4;
    float gb4[4];
#pragma unroll
    for (int r2 = 0; r2 < 4; ++r2) gb4[r2] = (kh == 0) ? gb[r0 + r2] : 0.f;
#pragma unroll
    for (int j = 0; j < 8; ++j) {
      const int col = (mh * 8 + j) * 16 + lmod;
#pragma unroll
      for (int r2 = 0; r2 < 4; ++r2) {
        hp[(size_t)(r0 + r2) * 256 + col] = acc[a][j][r2] + gb4[r2];
      }
    }
  }
}

// ---------------- level 0: one term per block, sums the two K-half partials
__global__ __launch_bounds__(256) void level0_kernel(
    const float* __restrict__ yinA, const float* __restrict__ yinB,
    const float* __restrict__ w,
    const float* __restrict__ bia, const float* __restrict__ gam,
    const float* __restrict__ bet, const float* __restrict__ p,
    const float* __restrict__ q, const float* __restrict__ r,
    const float* __restrict__ s, float* __restrict__ yout,
    float* __restrict__ out, int inl, int off) {
  const int t = blockIdx.x;
  const int b = threadIdx.x;
  __shared__ float wls[6 * 10];
  __shared__ float part[4][12];
  __shared__ float stats[12];
  const float* wt = w + (size_t)t * 6 * inl;
  for (int i = b; i < 6 * inl; i += 256) wls[i] = wt[i];
  __syncthreads();

  float z[6];
#pragma unroll
  for (int h = 0; h < 6; ++h) z[h] = bia[t * 6 + h];
  const float* ypA = yinA + (size_t)t * inl * 256 + b;
  const float* ypB = yinB + (size_t)t * inl * 256 + b;
  for (int i = 0; i < inl; ++i) {
    float v = ypA[(size_t)i * 256] + ypB[(size_t)i * 256];
#pragma unroll
    for (int h = 0; h < 6; ++h) z[h] = fmaf(v, wls[h * inl + i], z[h]);
  }
#pragma unroll
  for (int h = 0; h < 6; ++h) z[h] = tanhf(z[h]);

  float sm[6], sq[6];
#pragma unroll
  for (int h = 0; h < 6; ++h) { sm[h] = z[h]; sq[h] = z[h] * z[h]; }
#pragma unroll
  for (int o = 32; o > 0; o >>= 1) {
#pragma unroll
    for (int h = 0; h < 6; ++h) {
      sm[h] += __shfl_down(sm[h], o);
      sq[h] += __shfl_down(sq[h], o);
    }
  }
  const int lane = b & 63, wvi = b >> 6;
  if (lane == 0) {
#pragma unroll
    for (int h = 0; h < 6; ++h) { part[wvi][h] = sm[h]; part[wvi][6 + h] = sq[h]; }
  }
  __syncthreads();
  if (b < 6) {
    float msum = part[0][b] + part[1][b] + part[2][b] + part[3][b];
    float qsum = part[0][6 + b] + part[1][6 + b] + part[2][6 + b] + part[3][6 + b];
    float m = msum * (1.f / 256.f);
    float var = qsum * (1.f / 256.f) - m * m;
    stats[b] = m;
    stats[6 + b] = rsqrtf(var + EPS);
  }
  __syncthreads();

  float a = q[t];
#pragma unroll
  for (int h = 0; h < 6; ++h) {
    float yy = (z[h] - stats[h]) * stats[6 + h] * gam[t * 6 + h] + bet[t * 6 + h];
    yout[((size_t)t * 6 + h) * 256 + b] = yy;
    a = fmaf(yy, p[t * 6 + h], a);
  }
  out[(size_t)b * NOUT + off + t] = tanhf(a) * r[t] + s[t];
}

// ---------------- levels 1..2: one term per block
__global__ __launch_bounds__(256) void level_kernel(
    const float* __restrict__ yin, const float* __restrict__ w,
    const float* __restrict__ bia, const float* __restrict__ gam,
    const float* __restrict__ bet, const float* __restrict__ p,
    const float* __restrict__ q, const float* __restrict__ r,
    const float* __restrict__ s, float* __restrict__ yout,
    float* __restrict__ out, int inl, int off) {
  const int t = blockIdx.x;
  const int b = threadIdx.x;
  __shared__ float wls[6 * 48];
  __shared__ float part[4][12];
  __shared__ float stats[12];
  const float* wt = w + (size_t)t * 6 * inl;
  for (int i = b; i < 6 * inl; i += 256) wls[i] = wt[i];
  __syncthreads();

  float z[6];
#pragma unroll
  for (int h = 0; h < 6; ++h) z[h] = bia[t * 6 + h];
  const float* yp = yin + (size_t)t * inl * 256 + b;
  for (int i = 0; i < inl; ++i) {
    float v = yp[(size_t)i * 256];
#pragma unroll
    for (int h = 0; h < 6; ++h) z[h] = fmaf(v, wls[h * inl + i], z[h]);
  }
#pragma unroll
  for (int h = 0; h < 6; ++h) z[h] = tanhf(z[h]);

  float sm[6], sq[6];
#pragma unroll
  for (int h = 0; h < 6; ++h) { sm[h] = z[h]; sq[h] = z[h] * z[h]; }
#pragma unroll
  for (int o = 32; o > 0; o >>= 1) {
#pragma unroll
    for (int h = 0; h < 6; ++h) {
      sm[h] += __shfl_down(sm[h], o);
      sq[h] += __shfl_down(sq[h], o);
    }
  }
  const int lane = b & 63, wvi = b >> 6;
  if (lane == 0) {
#pragma unroll
    for (int h = 0; h < 6; ++h) { part[wvi][h] = sm[h]; part[wvi][6 + h] = sq[h]; }
  }
  __syncthreads();
  if (b < 6) {
    float msum = part[0][b] + part[1][b] + part[2][b] + part[3][b];
    float qsum = part[0][6 + b] + part[1][6 + b] + part[2][6 + b] + part[3][6 + b];
    float m = msum * (1.f / 256.f);
    float var = qsum * (1.f / 256.f) - m * m;
    stats[b] = m;
    stats[6 + b] = rsqrtf(var + EPS);
  }
  __syncthreads();

  float a = q[t];
#pragma unroll
  for (int h = 0; h < 6; ++h) {
    float yy = (z[h] - stats[h]) * stats[6 + h] * gam[t * 6 + h] + bet[t * 6 + h];
    yout[((size_t)t * 6 + h) * 256 + b] = yy;
    a = fmaf(yy, p[t * 6 + h], a);
  }
  out[(size_t)b * NOUT + off + t] = tanhf(a) * r[t] + s[t];
}

// ---------------- merged level-3 (inl=192, 1 term) + final head; single block
__global__ __launch_bounds__(256) void level3_final_kernel(
    const float* __restrict__ y2,
    const float* __restrict__ w3, const float* __restrict__ b3,
    const float* __restrict__ g3, const float* __restrict__ e3,
    const float* __restrict__ p3, const float* __restrict__ q3,
    const float* __restrict__ r3, const float* __restrict__ s3,
    const float* __restrict__ fw, const float* __restrict__ fb,
    const float* __restrict__ fg, const float* __restrict__ fe,
    const float* __restrict__ pw, const float* __restrict__ pb,
    const float* __restrict__ rw, const float* __restrict__ rb,
    float* __restrict__ out) {
  const int b = threadIdx.x;
  __shared__ float wls[6 * 192];
  __shared__ float part[4][24];
  __shared__ float stats[24];
  for (int i = b; i < 6 * 192; i += 256) wls[i] = w3[i];
  __syncthreads();

  float z[6];
#pragma unroll
  for (int h = 0; h < 6; ++h) z[h] = b3[h];
  const float* yp = y2 + b;
  for (int i = 0; i < 192; ++i) {
    float v = yp[(size_t)i * 256];
#pragma unroll
    for (int h = 0; h < 6; ++h) z[h] = fmaf(v, wls[h * 192 + i], z[h]);
  }
#pragma unroll
  for (int h = 0; h < 6; ++h) z[h] = tanhf(z[h]);

  const int lane = b & 63, wvi = b >> 6;
  {
    float sm[6], sq[6];
#pragma unroll
    for (int h = 0; h < 6; ++h) { sm[h] = z[h]; sq[h] = z[h] * z[h]; }
#pragma unroll
    for (int o = 32; o > 0; o >>= 1) {
#pragma unroll
      for (int h = 0; h < 6; ++h) {
        sm[h] += __shfl_down(sm[h], o);
        sq[h] += __shfl_down(sq[h], o);
      }
    }
    if (lane == 0) {
#pragma unroll
      for (int h = 0; h < 6; ++h) { part[wvi][h] = sm[h]; part[wvi][6 + h] = sq[h]; }
    }
    __syncthreads();
    if (b < 6) {
      float msum = part[0][b] + part[1][b] + part[2][b] + part[3][b];
      float qsum = part[0][6 + b] + part[1][6 + b] + part[2][6 + b] + part[3][6 + b];
      float m = msum * (1.f / 256.f);
      float var = qsum * (1.f / 256.f) - m * m;
      stats[b] = m;
      stats[6 + b] = rsqrtf(var + EPS);
    }
    __syncthreads();
  }

  float yr[6];
  float a3 = q3[0];
#pragma unroll
  for (int h = 0; h < 6; ++h) {
    yr[h] = (z[h] - stats[h]) * stats[6 + h] * g3[h] + e3[h];
    a3 = fmaf(yr[h], p3[h], a3);
  }
  out[(size_t)b * NOUT + 2336] = tanhf(a3) * r3[0] + s3[0];
  __syncthreads();

  float zf[12];
#pragma unroll
  for (int j = 0; j < 12; ++j) {
    float a = fb[j];
#pragma unroll
    for (int h = 0; h < 6; ++h) a = fmaf(yr[h], fw[j * 6 + h], a);
    zf[j] = tanhf(a);
  }
  {
    float sm[12], sq[12];
#pragma unroll
    for (int j = 0; j < 12; ++j) { sm[j] = zf[j]; sq[j] = zf[j] * zf[j]; }
#pragma unroll
    for (int o = 32; o > 0; o >>= 1) {
#pragma unroll
      for (int j = 0; j < 12; ++j) {
        sm[j] += __shfl_down(sm[j], o);
        sq[j] += __shfl_down(sq[j], o);
      }
    }
    if (lane == 0) {
#pragma unroll
      for (int j = 0; j < 12; ++j) { part[wvi][j] = sm[j]; part[wvi][12 + j] = sq[j]; }
    }
    __syncthreads();
    if (b < 12) {
      float msum = part[0][b] + part[1][b] + part[2][b] + part[3][b];
      float qsum = part[0][12 + b] + part[1][12 + b] + part[2][12 + b] + part[3][12 + b];
      float m = msum * (1.f / 256.f);
      float var = qsum * (1.f / 256.f) - m * m;
      stats[b] = m;
      stats[12 + b] = rsqrtf(var + EPS);
    }
    __syncthreads();
  }
  float a = pb[0];
#pragma unroll
  for (int j = 0; j < 12; ++j) {
    float of = (zf[j] - stats[j]) * stats[12 + j] * fg[j] + fe[j];
    a = fmaf(of, pw[j], a);
  }
  out[(size_t)b * NOUT + 2337] = tanhf(a) * rw[0] + rb[0];
}

extern "C" void kernel_launch(void* const* d_in, const int* in_sizes, int n_in,
                              void* d_out, int out_size, void* d_ws, size_t ws_size,
                              hipStream_t stream) {
  const float* x  = (const float*)d_in[0];
  const float* gW = (const float*)d_in[1];
  const float* gb = (const float*)d_in[2];
  float* out = (float*)d_out;

  char* wsb = (char*)d_ws;
  u16* XBp = (u16*)wsb;                              // 256*3008 bf16 (packed) = 1.54MB
  float* h0 = (float*)(wsb + 1540096);               // 2 x [20480][256] K-half partials
  float* y0 = h0 + (size_t)2 * 20480 * 256;          // [12288][256]
  float* y1 = y0 + (size_t)12288 * 256;              // [1536][256]
  float* y2 = y1 + (size_t)1536 * 256;               // [192][256]

  cvt_pack_kernel<<<dim3(376), dim3(256), 0, stream>>>(x, XBp);
  gemm_leaf<<<dim3(640), dim3(256), 0, stream>>>(gW, gb, XBp, h0);

  level0_kernel<<<dim3(2048), dim3(256), 0, stream>>>(
      h0, h0 + (size_t)20480 * 256,
      (const float*)d_in[3], (const float*)d_in[4], (const float*)d_in[5],
      (const float*)d_in[6], (const float*)d_in[7], (const float*)d_in[8],
      (const float*)d_in[9], (const float*)d_in[10], y0, out, 10, 0);

#define LV(base, yin, yout, inl, off, grid)                                           \
  level_kernel<<<dim3(grid), dim3(256), 0, stream>>>(                                 \
      yin, (const float*)d_in[base], (const float*)d_in[base + 1],                    \
      (const float*)d_in[base + 2], (const float*)d_in[base + 3],                     \
      (const float*)d_in[base + 4], (const float*)d_in[base + 5],                     \
      (const float*)d_in[base + 6], (const float*)d_in[base + 7], yout, out, inl, off)

  LV(11, y0, y1, 48,  2048, 256);
  LV(19, y1, y2, 48,  2304, 32);
#undef LV

  level3_final_kernel<<<dim3(1), dim3(256), 0, stream>>>(
      y2,
      (const float*)d_in[27], (const float*)d_in[28], (const float*)d_in[29],
      (const float*)d_in[30], (const float*)d_in[31], (const float*)d_in[32],
      (const float*)d_in[33], (const float*)d_in[34],
      (const float*)d_in[35], (const float*)d_in[36], (const float*)d_in[37],
      (const float*)d_in[38], (const float*)d_in[39], (const float*)d_in[40],
      (const float*)d_in[41], (const float*)d_in[42], out);
}

// Round 20
// 129.241 us; speedup vs baseline: 2.0085x; 1.0643x over previous
//
#include <hip/hip_runtime.h>
#include <hip/hip_bf16.h>
#include <stdint.h>

#define EPS 1e-5f
#define NOUT 2338   // 2048+256+32+1+1 output cols per batch row

typedef __bf16 bf16x8 __attribute__((ext_vector_type(8)));
typedef float f32x4 __attribute__((ext_vector_type(4)));
typedef unsigned short u16;

__device__ __forceinline__ uint32_t pack2f(float lo, float hi) {
  union { __bf16 h[2]; uint32_t u; } r;
  r.h[0] = (__bf16)lo;   // v_cvt_pk_bf16_f32
  r.h[1] = (__bf16)hi;
  return r.u;
}

// ---------------- kernel 0: x [256][3008] f32 -> bf16, packed in MFMA B-frag tile order
// XBp[ks][kb][m][e] : ks in [0,94), kb in [0,4), m in [0,256), e in [0,8)
__global__ __launch_bounds__(256) void cvt_pack_kernel(const float* __restrict__ x,
                                                       u16* __restrict__ xbp) {
  const int i = blockIdx.x * 256 + threadIdx.x;   // 96256 total
  const int ks = i >> 10;
  const int rem = i & 1023;
  const int kb = rem >> 8;
  const int m = rem & 255;
  const f32x4* src = (const f32x4*)(x + (size_t)m * 3008 + ks * 32 + kb * 8);
  f32x4 a = src[0], b = src[1];
  uint4 o;
  o.x = pack2f(a.x, a.y);
  o.y = pack2f(a.z, a.w);
  o.z = pack2f(b.x, b.y);
  o.w = pack2f(b.z, b.w);
  ((uint4*)xbp)[i] = o;
}

// ---------------- kernel 1: leaf GEMM — 8-wave blocks, 128-row tile, K-split 3.
// C [20480 x 256] = W[20480 x 3008] * X^T.  16x16x32 bf16 MFMA.
// Grid 480: bid/3 = 128-row tile (n0), bid%3 = K-third (32/31/31 steps).
// Block 512 thr (8 waves). Wave w: rh=w>>1 (32 rows = 2 A-frags), mh=w&1 (8 m-tiles).
// One 16KB X tile serves all 128 rows (2x the reuse of the 4-wave variant);
// 16 waves/CU resident (2 blocks x 8 waves) vs 12 for the 4-wave variant.
__global__ __launch_bounds__(512, 4) void gemm_leaf(const float* __restrict__ W,
                                                    const float* __restrict__ gb,
                                                    const u16* __restrict__ XBp,
                                                    float* __restrict__ hout) {
  __shared__ __align__(16) u16 xl[2][8192];     // 2 x 16KB X tile [kb][m][e]
  __shared__ __align__(16) float wlds[2][4096]; // 2 x 16KB W slab [row(128)][32f] swizzled
  const int tid = threadIdx.x;
  const int w = tid >> 6;         // wave 0..7
  const int lane = tid & 63;
  const int rh = w >> 1;          // row-group 0..3 (32 rows each)
  const int mh = w & 1;           // m-half 0..1
  const int lquad = lane >> 4;    // k-group 0..3
  const int lmod = lane & 15;
  const int n0 = (blockIdx.x / 3) * 128;
  const int kh = blockIdx.x % 3;
  const int kbase = kh * 32 - ((kh >= 2) ? 1 : 0);   // 0, 32, 63
  const int nst = (kh == 0) ? 32 : 31;               // 32+31+31 = 94

  f32x4 acc[2][8];
#pragma unroll
  for (int a = 0; a < 2; ++a)
#pragma unroll
    for (int j = 0; j < 8; ++j) acc[a][j] = (f32x4){0.f, 0.f, 0.f, 0.f};

  // X stage: 16 coalesced 1KB chunks (2 per wave); chunk c = (w*2+p)*64 lanes of 8 u16
#define STAGE_X(ks, buf)                                                                \
  {                                                                                     \
    _Pragma("unroll")                                                                   \
    for (int p = 0; p < 2; ++p) {                                                       \
      const int c = (w * 2 + p) * 64;                                                   \
      const u16* src = XBp + (size_t)(ks) * 8192 + (size_t)(c + lane) * 8;              \
      u16* dst = &xl[buf][(size_t)c * 8];                                               \
      __builtin_amdgcn_global_load_lds((const __attribute__((address_space(1))) void*)src, \
                                       (__attribute__((address_space(3))) void*)dst,    \
                                       16, 0, 0);                                       \
    }                                                                                   \
  }

  // W stage: 16 coalesced 1KB instrs (2 per wave); instr q covers rows q*8..q*8+7.
  // LDS[row][b] = W[n0+row][ks*32f + ((b ^ ((row&7)<<4))>>2)] via pre-swizzled source.
  const int wr0 = w * 2, wr1 = w * 2 + 1;
  const int lrow = lane >> 3;                                   // row-in-instr 0..7
  const int lswf = ((((lane & 7) * 16) ^ (lrow << 4)) >> 2);    // src float offset
  const float* wsrc0 = W + (size_t)(n0 + wr0 * 8 + lrow) * 3008 + lswf;
  const float* wsrc1 = W + (size_t)(n0 + wr1 * 8 + lrow) * 3008 + lswf;
#define STAGE_W(ks, buf)                                                                \
  {                                                                                     \
    __builtin_amdgcn_global_load_lds(                                                   \
        (const __attribute__((address_space(1))) void*)(wsrc0 + (size_t)(ks) * 32),     \
        (__attribute__((address_space(3))) void*)&wlds[buf][wr0 * 256], 16, 0, 0);      \
    __builtin_amdgcn_global_load_lds(                                                   \
        (const __attribute__((address_space(1))) void*)(wsrc1 + (size_t)(ks) * 32),     \
        (__attribute__((address_space(3))) void*)&wlds[buf][wr1 * 256], 16, 0, 0);      \
  }

  STAGE_X(kbase, 0);
  STAGE_W(kbase, 0);

  const int xorv = (lmod & 7) << 4;
  for (int s = 0; s < nst; ++s) {
    const int buf = s & 1;
    __syncthreads();   // drains stage(s)
    if (s + 1 < nst) {
      STAGE_X(kbase + s + 1, buf ^ 1);
      STAGE_W(kbase + s + 1, buf ^ 1);
    }
    __builtin_amdgcn_sched_barrier(0);   // stage issues before compute

    const float* wbase = &wlds[buf][0];
    const u16* xb = &xl[buf][(size_t)lquad * 2048 + mh * 1024 + lmod * 8];
    union { uint32_t u32[4]; bf16x8 v; } af[2];
#pragma unroll
    for (int a = 0; a < 2; ++a) {
      const int row = rh * 32 + a * 16 + lmod;
      const int fb = row * 32;
      const f32x4 wlo = *(const f32x4*)(wbase + fb + (((lquad * 32) ^ xorv) >> 2));
      const f32x4 whi = *(const f32x4*)(wbase + fb + (((lquad * 32 + 16) ^ xorv) >> 2));
      af[a].u32[0] = pack2f(wlo.x, wlo.y);
      af[a].u32[1] = pack2f(wlo.z, wlo.w);
      af[a].u32[2] = pack2f(whi.x, whi.y);
      af[a].u32[3] = pack2f(whi.z, whi.w);
    }
#pragma unroll
    for (int j = 0; j < 8; ++j) {
      const bf16x8 bfrag = *(const bf16x8*)(xb + j * 128);
      acc[0][j] = __builtin_amdgcn_mfma_f32_16x16x32_bf16(af[0].v, bfrag, acc[0][j], 0, 0, 0);
      acc[1][j] = __builtin_amdgcn_mfma_f32_16x16x32_bf16(af[1].v, bfrag, acc[1][j], 0, 0, 0);
    }
  }

#undef STAGE_W
#undef STAGE_X

  // store partial: hp = hout + kh*20480*256; kh==0 adds gb.
  float* hp = hout + (size_t)kh * 20480 * 256;
#pragma unroll
  for (int a = 0; a < 2; ++a) {
    const int r0 = n0 + rh * 32 + a * 16 + lquad * 4;
    float gb4[4];
#pragma unroll
    for (int r2 = 0; r2 < 4; ++r2) gb4[r2] = (kh == 0) ? gb[r0 + r2] : 0.f;
#pragma unroll
    for (int j = 0; j < 8; ++j) {
      const int col = (mh * 8 + j) * 16 + lmod;
#pragma unroll
      for (int r2 = 0; r2 < 4; ++r2) {
        hp[(size_t)(r0 + r2) * 256 + col] = acc[a][j][r2] + gb4[r2];
      }
    }
  }
}

// ---------------- level 0: one term per block, sums the three K-third partials
__global__ __launch_bounds__(256) void level0_kernel(
    const float* __restrict__ yin, const float* __restrict__ w,
    const float* __restrict__ bia, const float* __restrict__ gam,
    const float* __restrict__ bet, const float* __restrict__ p,
    const float* __restrict__ q, const float* __restrict__ r,
    const float* __restrict__ s, float* __restrict__ yout,
    float* __restrict__ out, int inl, int off) {
  const int t = blockIdx.x;
  const int b = threadIdx.x;
  const size_t P = (size_t)20480 * 256;
  __shared__ float wls[6 * 10];
  __shared__ float part[4][12];
  __shared__ float stats[12];
  const float* wt = w + (size_t)t * 6 * inl;
  for (int i = b; i < 6 * inl; i += 256) wls[i] = wt[i];
  __syncthreads();

  float z[6];
#pragma unroll
  for (int h = 0; h < 6; ++h) z[h] = bia[t * 6 + h];
  const float* yp = yin + (size_t)t * inl * 256 + b;
  for (int i = 0; i < inl; ++i) {
    const size_t o = (size_t)i * 256;
    float v = yp[o] + yp[P + o] + yp[2 * P + o];
#pragma unroll
    for (int h = 0; h < 6; ++h) z[h] = fmaf(v, wls[h * inl + i], z[h]);
  }
#pragma unroll
  for (int h = 0; h < 6; ++h) z[h] = tanhf(z[h]);

  float sm[6], sq[6];
#pragma unroll
  for (int h = 0; h < 6; ++h) { sm[h] = z[h]; sq[h] = z[h] * z[h]; }
#pragma unroll
  for (int o = 32; o > 0; o >>= 1) {
#pragma unroll
    for (int h = 0; h < 6; ++h) {
      sm[h] += __shfl_down(sm[h], o);
      sq[h] += __shfl_down(sq[h], o);
    }
  }
  const int lane = b & 63, wvi = b >> 6;
  if (lane == 0) {
#pragma unroll
    for (int h = 0; h < 6; ++h) { part[wvi][h] = sm[h]; part[wvi][6 + h] = sq[h]; }
  }
  __syncthreads();
  if (b < 6) {
    float msum = part[0][b] + part[1][b] + part[2][b] + part[3][b];
    float qsum = part[0][6 + b] + part[1][6 + b] + part[2][6 + b] + part[3][6 + b];
    float m = msum * (1.f / 256.f);
    float var = qsum * (1.f / 256.f) - m * m;
    stats[b] = m;
    stats[6 + b] = rsqrtf(var + EPS);
  }
  __syncthreads();

  float a = q[t];
#pragma unroll
  for (int h = 0; h < 6; ++h) {
    float yy = (z[h] - stats[h]) * stats[6 + h] * gam[t * 6 + h] + bet[t * 6 + h];
    yout[((size_t)t * 6 + h) * 256 + b] = yy;
    a = fmaf(yy, p[t * 6 + h], a);
  }
  out[(size_t)b * NOUT + off + t] = tanhf(a) * r[t] + s[t];
}

// ---------------- levels 1..2: one term per block
__global__ __launch_bounds__(256) void level_kernel(
    const float* __restrict__ yin, const float* __restrict__ w,
    const float* __restrict__ bia, const float* __restrict__ gam,
    const float* __restrict__ bet, const float* __restrict__ p,
    const float* __restrict__ q, const float* __restrict__ r,
    const float* __restrict__ s, float* __restrict__ yout,
    float* __restrict__ out, int inl, int off) {
  const int t = blockIdx.x;
  const int b = threadIdx.x;
  __shared__ float wls[6 * 48];
  __shared__ float part[4][12];
  __shared__ float stats[12];
  const float* wt = w + (size_t)t * 6 * inl;
  for (int i = b; i < 6 * inl; i += 256) wls[i] = wt[i];
  __syncthreads();

  float z[6];
#pragma unroll
  for (int h = 0; h < 6; ++h) z[h] = bia[t * 6 + h];
  const float* yp = yin + (size_t)t * inl * 256 + b;
  for (int i = 0; i < inl; ++i) {
    float v = yp[(size_t)i * 256];
#pragma unroll
    for (int h = 0; h < 6; ++h) z[h] = fmaf(v, wls[h * inl + i], z[h]);
  }
#pragma unroll
  for (int h = 0; h < 6; ++h) z[h] = tanhf(z[h]);

  float sm[6], sq[6];
#pragma unroll
  for (int h = 0; h < 6; ++h) { sm[h] = z[h]; sq[h] = z[h] * z[h]; }
#pragma unroll
  for (int o = 32; o > 0; o >>= 1) {
#pragma unroll
    for (int h = 0; h < 6; ++h) {
      sm[h] += __shfl_down(sm[h], o);
      sq[h] += __shfl_down(sq[h], o);
    }
  }
  const int lane = b & 63, wvi = b >> 6;
  if (lane == 0) {
#pragma unroll
    for (int h = 0; h < 6; ++h) { part[wvi][h] = sm[h]; part[wvi][6 + h] = sq[h]; }
  }
  __syncthreads();
  if (b < 6) {
    float msum = part[0][b] + part[1][b] + part[2][b] + part[3][b];
    float qsum = part[0][6 + b] + part[1][6 + b] + part[2][6 + b] + part[3][6 + b];
    float m = msum * (1.f / 256.f);
    float var = qsum * (1.f / 256.f) - m * m;
    stats[b] = m;
    stats[6 + b] = rsqrtf(var + EPS);
  }
  __syncthreads();

  float a = q[t];
#pragma unroll
  for (int h = 0; h < 6; ++h) {
    float yy = (z[h] - stats[h]) * stats[6 + h] * gam[t * 6 + h] + bet[t * 6 + h];
    yout[((size_t)t * 6 + h) * 256 + b] = yy;
    a = fmaf(yy, p[t * 6 + h], a);
  }
  out[(size_t)b * NOUT + off + t] = tanhf(a) * r[t] + s[t];
}

// ---------------- merged level-3 (inl=192, 1 term) + final head; single block
__global__ __launch_bounds__(256) void level3_final_kernel(
    const float* __restrict__ y2,
    const float* __restrict__ w3, const float* __restrict__ b3,
    const float* __restrict__ g3, const float* __restrict__ e3,
    const float* __restrict__ p3, const float* __restrict__ q3,
    const float* __restrict__ r3, const float* __restrict__ s3,
    const float* __restrict__ fw, const float* __restrict__ fb,
    const float* __restrict__ fg, const float* __restrict__ fe,
    const float* __restrict__ pw, const float* __restrict__ pb,
    const float* __restrict__ rw, const float* __restrict__ rb,
    float* __restrict__ out) {
  const int b = threadIdx.x;
  __shared__ float wls[6 * 192];
  __shared__ float part[4][24];
  __shared__ float stats[24];
  for (int i = b; i < 6 * 192; i += 256) wls[i] = w3[i];
  __syncthreads();

  float z[6];
#pragma unroll
  for (int h = 0; h < 6; ++h) z[h] = b3[h];
  const float* yp = y2 + b;
  for (int i = 0; i < 192; ++i) {
    float v = yp[(size_t)i * 256];
#pragma unroll
    for (int h = 0; h < 6; ++h) z[h] = fmaf(v, wls[h * 192 + i], z[h]);
  }
#pragma unroll
  for (int h = 0; h < 6; ++h) z[h] = tanhf(z[h]);

  const int lane = b & 63, wvi = b >> 6;
  {
    float sm[6], sq[6];
#pragma unroll
    for (int h = 0; h < 6; ++h) { sm[h] = z[h]; sq[h] = z[h] * z[h]; }
#pragma unroll
    for (int o = 32; o > 0; o >>= 1) {
#pragma unroll
      for (int h = 0; h < 6; ++h) {
        sm[h] += __shfl_down(sm[h], o);
        sq[h] += __shfl_down(sq[h], o);
      }
    }
    if (lane == 0) {
#pragma unroll
      for (int h = 0; h < 6; ++h) { part[wvi][h] = sm[h]; part[wvi][6 + h] = sq[h]; }
    }
    __syncthreads();
    if (b < 6) {
      float msum = part[0][b] + part[1][b] + part[2][b] + part[3][b];
      float qsum = part[0][6 + b] + part[1][6 + b] + part[2][6 + b] + part[3][6 + b];
      float m = msum * (1.f / 256.f);
      float var = qsum * (1.f / 256.f) - m * m;
      stats[b] = m;
      stats[6 + b] = rsqrtf(var + EPS);
    }
    __syncthreads();
  }

  float yr[6];
  float a3 = q3[0];
#pragma unroll
  for (int h = 0; h < 6; ++h) {
    yr[h] = (z[h] - stats[h]) * stats[6 + h] * g3[h] + e3[h];
    a3 = fmaf(yr[h], p3[h], a3);
  }
  out[(size_t)b * NOUT + 2336] = tanhf(a3) * r3[0] + s3[0];
  __syncthreads();

  float zf[12];
#pragma unroll
  for (int j = 0; j < 12; ++j) {
    float a = fb[j];
#pragma unroll
    for (int h = 0; h < 6; ++h) a = fmaf(yr[h], fw[j * 6 + h], a);
    zf[j] = tanhf(a);
  }
  {
    float sm[12], sq[12];
#pragma unroll
    for (int j = 0; j < 12; ++j) { sm[j] = zf[j]; sq[j] = zf[j] * zf[j]; }
#pragma unroll
    for (int o = 32; o > 0; o >>= 1) {
#pragma unroll
      for (int j = 0; j < 12; ++j) {
        sm[j] += __shfl_down(sm[j], o);
        sq[j] += __shfl_down(sq[j], o);
      }
    }
    if (lane == 0) {
#pragma unroll
      for (int j = 0; j < 12; ++j) { part[wvi][j] = sm[j]; part[wvi][12 + j] = sq[j]; }
    }
    __syncthreads();
    if (b < 12) {
      float msum = part[0][b] + part[1][b] + part[2][b] + part[3][b];
      float qsum = part[0][12 + b] + part[1][12 + b] + part[2][12 + b] + part[3][12 + b];
      float m = msum * (1.f / 256.f);
      float var = qsum * (1.f / 256.f) - m * m;
      stats[b] = m;
      stats[12 + b] = rsqrtf(var + EPS);
    }
    __syncthreads();
  }
  float a = pb[0];
#pragma unroll
  for (int j = 0; j < 12; ++j) {
    float of = (zf[j] - stats[j]) * stats[12 + j] * fg[j] + fe[j];
    a = fmaf(of, pw[j], a);
  }
  out[(size_t)b * NOUT + 2337] = tanhf(a) * rw[0] + rb[0];
}

extern "C" void kernel_launch(void* const* d_in, const int* in_sizes, int n_in,
                              void* d_out, int out_size, void* d_ws, size_t ws_size,
                              hipStream_t stream) {
  const float* x  = (const float*)d_in[0];
  const float* gW = (const float*)d_in[1];
  const float* gb = (const float*)d_in[2];
  float* out = (float*)d_out;

  char* wsb = (char*)d_ws;
  u16* XBp = (u16*)wsb;                              // 256*3008 bf16 (packed) = 1.54MB
  float* h0 = (float*)(wsb + 1540096);               // 3 x [20480][256] K-third partials
  float* y0 = h0 + (size_t)3 * 20480 * 256;          // [12288][256]
  float* y1 = y0 + (size_t)12288 * 256;              // [1536][256]
  float* y2 = y1 + (size_t)1536 * 256;               // [192][256]

  cvt_pack_kernel<<<dim3(376), dim3(256), 0, stream>>>(x, XBp);
  gemm_leaf<<<dim3(480), dim3(512), 0, stream>>>(gW, gb, XBp, h0);

  level0_kernel<<<dim3(2048), dim3(256), 0, stream>>>(
      h0,
      (const float*)d_in[3], (const float*)d_in[4], (const float*)d_in[5],
      (const float*)d_in[6], (const float*)d_in[7], (const float*)d_in[8],
      (const float*)d_in[9], (const float*)d_in[10], y0, out, 10, 0);

#define LV(base, yin, yout, inl, off, grid)                                           \
  level_kernel<<<dim3(grid), dim3(256), 0, stream>>>(                                 \
      yin, (const float*)d_in[base], (const float*)d_in[base + 1],                    \
      (const float*)d_in[base + 2], (const float*)d_in[base + 3],                     \
      (const float*)d_in[base + 4], (const float*)d_in[base + 5],                     \
      (const float*)d_in[base + 6], (const float*)d_in[base + 7], yout, out, inl, off)

  LV(11, y0, y1, 48,  2048, 256);
  LV(19, y1, y2, 48,  2304, 32);
#undef LV

  level3_final_kernel<<<dim3(1), dim3(256), 0, stream>>>(
      y2,
      (const float*)d_in[27], (const float*)d_in[28], (const float*)d_in[29],
      (const float*)d_in[30], (const float*)d_in[31], (const float*)d_in[32],
      (const float*)d_in[33], (const float*)d_in[34],
      (const float*)d_in[35], (const float*)d_in[36], (const float*)d_in[37],
      (const float*)d_in[38], (const float*)d_in[39], (const float*)d_in[40],
      (const float*)d_in[41], (const float*)d_in[42], out);
}